// Round 1
// baseline (25.794 us; speedup 1.0000x reference)
//
#include <hip/hip_runtime.h>

// CrossConvV2: B=2, n=1024, d=3, f=3, m=26 probes, k=5 convs, o=6 out_feats.
// out[b,l] = [coords(3) | leakyrelu( (wf(b,l,:,:)*10/n flat 78) @ W[k] + b[k] ) (30)]
// wf[b,l,m,ff] = sum_nn 1/(|c_nn - c_l - p_m|^2 + 10) * feats[nn,ff]
// Using |c_nn - c_l - p|^2 + 10 = |d|^2 + 19 - 2 d.p  (|p|=3 for all probes).

#define NPROBE 26
#define NPTS   1024
#define COEFF  10.0f
#define NEG    0.3f

// probe points (DIST=3), precomputed from the reference formula
__device__ constexpr float PROBE[NPROBE][3] = {
  {-2.12132034f,  1.95984445f, -0.81179415f},
  {-2.12132034f,  1.95984445f,  0.81179415f},
  {-2.12132034f,  0.81179415f,  1.95984445f},
  {-2.12132034f, -0.81179415f,  1.95984445f},
  {-2.12132034f, -1.95984445f,  0.81179415f},
  {-2.12132034f, -1.95984445f, -0.81179415f},
  {-2.12132034f, -0.81179415f, -1.95984445f},
  {-2.12132034f,  0.81179415f, -1.95984445f},
  { 0.0f,         3.0f,         0.0f       },
  { 0.0f,         2.12132034f,  2.12132034f},
  { 0.0f,         0.0f,         3.0f       },
  { 0.0f,        -2.12132034f,  2.12132034f},
  { 0.0f,        -3.0f,         0.0f       },
  { 0.0f,        -2.12132034f, -2.12132034f},
  { 0.0f,         0.0f,        -3.0f       },
  { 0.0f,         2.12132034f, -2.12132034f},
  { 2.12132034f,  1.95984445f,  0.81179415f},
  { 2.12132034f,  0.81179415f,  1.95984445f},
  { 2.12132034f, -0.81179415f,  1.95984445f},
  { 2.12132034f, -1.95984445f,  0.81179415f},
  { 2.12132034f, -1.95984445f, -0.81179415f},
  { 2.12132034f, -0.81179415f, -1.95984445f},
  { 2.12132034f,  0.81179415f, -1.95984445f},
  { 2.12132034f,  1.95984445f, -0.81179415f},
  {-3.0f,         0.0f,         0.0f       },
  { 3.0f,         0.0f,         0.0f       },
};

__global__ __launch_bounds__(256) void crossconv_kernel(
    const float* __restrict__ points,  // (2,1024,6)
    const float* __restrict__ W,       // (5,78,6)
    const float* __restrict__ bias,    // (5,6) flat 30
    float* __restrict__ out)           // (2,1024,33)
{
    const int lane = threadIdx.x & 63;
    const int wid  = blockIdx.x * (blockDim.x >> 6) + (threadIdx.x >> 6); // 0..2047
    const int b = wid >> 10;
    const float* batch = points + b * NPTS * 6;
    const float* crow  = batch + (wid & 1023) * 6;
    const float cx = crow[0], cy = crow[1], cz = crow[2];

    float acc[NPROBE][3];
    #pragma unroll
    for (int m = 0; m < NPROBE; ++m) { acc[m][0] = 0.f; acc[m][1] = 0.f; acc[m][2] = 0.f; }

    // each lane: 16 neighbors, stride 64 (coalesced rows of 24B)
    for (int it = 0; it < NPTS / 64; ++it) {
        const float* prow = batch + (it * 64 + lane) * 6;
        const float px = prow[0], py = prow[1], pz = prow[2];
        const float f0 = prow[3], f1 = prow[4], f2 = prow[5];
        const float dx = px - cx, dy = py - cy, dz = pz - cz;
        // |d|^2 + |p|^2 + COEFF = |d|^2 + 9 + 10
        const float base = fmaf(dx, dx, fmaf(dy, dy, fmaf(dz, dz, 19.0f)));
        #pragma unroll
        for (int m = 0; m < NPROBE; ++m) {
            float t = fmaf(-2.0f * PROBE[m][0], dx,
                      fmaf(-2.0f * PROBE[m][1], dy,
                      fmaf(-2.0f * PROBE[m][2], dz, base)));
            float w = __builtin_amdgcn_rcpf(t);   // 1/(sq+COEFF), ~1ulp
            acc[m][0] = fmaf(w, f0, acc[m][0]);
            acc[m][1] = fmaf(w, f1, acc[m][1]);
            acc[m][2] = fmaf(w, f2, acc[m][2]);
        }
    }

    // wave butterfly reduce: every lane ends with the full sums
    #pragma unroll
    for (int m = 0; m < NPROBE; ++m) {
        #pragma unroll
        for (int ff = 0; ff < 3; ++ff) {
            float v = acc[m][ff];
            #pragma unroll
            for (int off = 32; off > 0; off >>= 1)
                v += __shfl_xor(v, off, 64);
            acc[m][ff] = v;
        }
    }

    const float scale = COEFF / (float)NPTS;   // fold COEFF and /n
    float* orow = out + wid * 33;

    if (lane < 30) {
        const int k = lane / 6, o = lane % 6;
        const float* Wk = W + k * 78 * 6 + o;  // W[k, t, o], stride 6 over t
        float h = bias[lane];
        #pragma unroll
        for (int t = 0; t < 78; ++t)
            h = fmaf(acc[t / 3][t % 3] * scale, Wk[t * 6], h);
        h = (h > 0.f) ? h : NEG * h;
        orow[3 + lane] = h;
    } else if (lane < 33) {
        orow[lane - 30] = (lane == 30) ? cx : ((lane == 31) ? cy : cz);
    }
}

extern "C" void kernel_launch(void* const* d_in, const int* in_sizes, int n_in,
                              void* d_out, int out_size, void* d_ws, size_t ws_size,
                              hipStream_t stream) {
    const float* points = (const float*)d_in[0];  // 2*1024*6
    const float* W      = (const float*)d_in[1];  // 5*78*6
    const float* bias   = (const float*)d_in[2];  // 30
    float* out          = (float*)d_out;          // 2*1024*33
    // 2048 waves total, 4 waves/block -> 512 blocks
    crossconv_kernel<<<512, 256, 0, stream>>>(points, W, bias, out);
}

// Round 2
// 25.124 us; speedup vs baseline: 1.0267x; 1.0267x over previous
//
#include <hip/hip_runtime.h>

// CrossConvV2: B=2, n=1024, d=3, f=3, m=26 probes, k=5 convs, o=6 out_feats.
// out[b,l] = [coords(3) | leakyrelu( (wf flat 78 * 10/n) @ W[k] + b[k] ) (30)]
// wf[b,l,m,ff] = sum_nn 1/(|c_nn - c_l - p_m|^2 + 10) * feats[nn,ff]
// |c_nn - c_l - p|^2 + 10 = |d|^2 + 19 - 2 d.p   (|p| = 3 for all probes)
//
// R1 structure: wave = (center, probe-half). 4096 waves -> 4 waves/SIMD
// (R0 had 2048 -> 2/SIMD, latency-bound at 36% issue packing).
// Reduction: DPP row_shr/row_bcast full-rate adds (rocPRIM wave64 pattern)
// instead of ds-shuffle butterfly.

#define NPTS   1024
#define COEFF  10.0f
#define NEG    0.3f

__device__ constexpr float PROBE[26][3] = {
  {-2.12132034f,  1.95984445f, -0.81179415f},
  {-2.12132034f,  1.95984445f,  0.81179415f},
  {-2.12132034f,  0.81179415f,  1.95984445f},
  {-2.12132034f, -0.81179415f,  1.95984445f},
  {-2.12132034f, -1.95984445f,  0.81179415f},
  {-2.12132034f, -1.95984445f, -0.81179415f},
  {-2.12132034f, -0.81179415f, -1.95984445f},
  {-2.12132034f,  0.81179415f, -1.95984445f},
  { 0.0f,         3.0f,         0.0f       },
  { 0.0f,         2.12132034f,  2.12132034f},
  { 0.0f,         0.0f,         3.0f       },
  { 0.0f,        -2.12132034f,  2.12132034f},
  { 0.0f,        -3.0f,         0.0f       },
  { 0.0f,        -2.12132034f, -2.12132034f},
  { 0.0f,         0.0f,        -3.0f       },
  { 0.0f,         2.12132034f, -2.12132034f},
  { 2.12132034f,  1.95984445f,  0.81179415f},
  { 2.12132034f,  0.81179415f,  1.95984445f},
  { 2.12132034f, -0.81179415f,  1.95984445f},
  { 2.12132034f, -1.95984445f,  0.81179415f},
  { 2.12132034f, -1.95984445f, -0.81179415f},
  { 2.12132034f, -0.81179415f, -1.95984445f},
  { 2.12132034f,  0.81179415f, -1.95984445f},
  { 2.12132034f,  1.95984445f, -0.81179415f},
  {-3.0f,         0.0f,         0.0f       },
  { 3.0f,         0.0f,         0.0f       },
};

// wave64 sum-reduce via DPP (result valid in lane 63). rocPRIM pattern.
#define DPP_STEP(x, ctrl, rm, bm, bc)                                        \
  x += __int_as_float(__builtin_amdgcn_update_dpp(                           \
      0, __float_as_int(x), ctrl, rm, bm, bc))

__device__ __forceinline__ float wave_sum_to_lane63(float x) {
  DPP_STEP(x, 0x111, 0xf, 0xf, true);   // row_shr:1
  DPP_STEP(x, 0x112, 0xf, 0xf, true);   // row_shr:2
  DPP_STEP(x, 0x114, 0xf, 0xe, false);  // row_shr:4
  DPP_STEP(x, 0x118, 0xf, 0xc, false);  // row_shr:8
  DPP_STEP(x, 0x142, 0xa, 0xf, false);  // row_bcast:15 -> rows 1,3
  DPP_STEP(x, 0x143, 0xc, 0xf, false);  // row_bcast:31 -> rows 2,3
  return x;                              // lane 63 = full sum
}

template <int OFF>
__device__ __forceinline__ void run_main(const float* __restrict__ batch,
                                         int lane, float cx, float cy, float cz,
                                         float acc[13][3]) {
  for (int it = 0; it < NPTS / 64; ++it) {
    const float* prow = batch + (it * 64 + lane) * 6;
    const float2 q0 = *reinterpret_cast<const float2*>(prow);
    const float2 q1 = *reinterpret_cast<const float2*>(prow + 2);
    const float2 q2 = *reinterpret_cast<const float2*>(prow + 4);
    const float dx = q0.x - cx, dy = q0.y - cy, dz = q1.x - cz;
    const float f0 = q1.y, f1 = q2.x, f2 = q2.y;
    // |d|^2 + |p|^2 + COEFF = |d|^2 + 9 + 10
    const float base = fmaf(dx, dx, fmaf(dy, dy, fmaf(dz, dz, 19.0f)));
    #pragma unroll
    for (int j = 0; j < 13; ++j) {
      const float t = fmaf(-2.0f * PROBE[OFF + j][0], dx,
                      fmaf(-2.0f * PROBE[OFF + j][1], dy,
                      fmaf(-2.0f * PROBE[OFF + j][2], dz, base)));
      const float w = __builtin_amdgcn_rcpf(t);  // 1/(sq+COEFF)
      acc[j][0] = fmaf(w, f0, acc[j][0]);
      acc[j][1] = fmaf(w, f1, acc[j][1]);
      acc[j][2] = fmaf(w, f2, acc[j][2]);
    }
  }
}

__global__ __launch_bounds__(256, 4) void crossconv_kernel(
    const float* __restrict__ points,  // (2,1024,6)
    const float* __restrict__ W,       // (5,78,6)
    const float* __restrict__ bias,    // (5,6) flat 30
    float* __restrict__ out)           // (2,1024,33)
{
    __shared__ float sx[2][78];

    const int tid    = threadIdx.x;
    const int lane   = tid & 63;
    const int w      = tid >> 6;     // wave in block: 0..3
    const int cLocal = w >> 1;       // center within block: 0,1
    const int half   = w & 1;        // probe half: 0,1
    const int G      = blockIdx.x * 2 + cLocal;   // global center 0..2047

    const float* batch = points + (G >> 10) * (NPTS * 6);
    const float* crow  = points + G * 6;
    const float  cx = crow[0], cy = crow[1], cz = crow[2];

    float acc[13][3];
    #pragma unroll
    for (int j = 0; j < 13; ++j) { acc[j][0] = 0.f; acc[j][1] = 0.f; acc[j][2] = 0.f; }

    if (half == 0) run_main<0>(batch, lane, cx, cy, cz, acc);
    else           run_main<13>(batch, lane, cx, cy, cz, acc);

    // reduce each of 39 partials across the wave (full sum lands in lane 63)
    const float scale = COEFF / (float)NPTS;
    #pragma unroll
    for (int j = 0; j < 13; ++j) {
      #pragma unroll
      for (int ff = 0; ff < 3; ++ff)
        acc[j][ff] = wave_sum_to_lane63(acc[j][ff]) * scale;
    }

    if (lane == 63) {
      #pragma unroll
      for (int j = 0; j < 13; ++j) {
        sx[cLocal][half * 39 + j * 3 + 0] = acc[j][0];
        sx[cLocal][half * 39 + j * 3 + 1] = acc[j][1];
        sx[cLocal][half * 39 + j * 3 + 2] = acc[j][2];
      }
    }
    __syncthreads();

    // tail: waves 0,2 (half==0) do the 78->30 matmul + coords for their center
    if (half == 0) {
      float* orow = out + G * 33;
      if (lane < 30) {
        const int k = lane / 6, o = lane % 6;
        const float* Wk = W + k * (78 * 6) + o;  // W[k, t, o], stride 6 over t
        float h = bias[lane];
        #pragma unroll
        for (int t = 0; t < 78; ++t)
          h = fmaf(sx[cLocal][t], Wk[t * 6], h);
        h = (h > 0.f) ? h : NEG * h;
        orow[3 + lane] = h;
      } else if (lane < 33) {
        orow[lane - 30] = (lane == 30) ? cx : ((lane == 31) ? cy : cz);
      }
    }
}

extern "C" void kernel_launch(void* const* d_in, const int* in_sizes, int n_in,
                              void* d_out, int out_size, void* d_ws, size_t ws_size,
                              hipStream_t stream) {
    const float* points = (const float*)d_in[0];  // 2*1024*6
    const float* W      = (const float*)d_in[1];  // 5*78*6
    const float* bias   = (const float*)d_in[2];  // 30
    float* out          = (float*)d_out;          // 2*1024*33
    // 1024 blocks x 4 waves = 4096 waves = 2048 centers x 2 probe-halves
    crossconv_kernel<<<1024, 256, 0, stream>>>(points, W, bias, out);
}